// Round 7
// baseline (264.401 us; speedup 1.0000x reference)
//
#include <hip/hip_runtime.h>

// DarcyLoss: B=4096, C=2, H=W=64. Inputs (f32): model_out, target, x0_hat [B,2,64,64], var [B].
// loss = mean((mo-tg)^2) + mean_b( min(0.5*r_b^2/var_b, 27.6310211159) )
// r_b = (sum(eq0)+sum(bc)) / (64*64*3);  source f_s sums to 0 -> omitted.
//
// R7: ONE wave per batch, fully uniform float4 streaming.
//  Lane l: group g=l>>4 (row within 4-row block), cg=l&15 (owns cols 4cg..4cg+3).
//  Iteration t (0..15): wave loads rows 4t..4t+3 of p and q as ONE contiguous
//  1KB load each (p4[t*64+lane]), plus 2+2 nontemporal float4 of mo/tg.
//  Vertical stencil: rows r+-1 live in lanes l+-16 (wrap -> prev/next iteration
//  registers, selected by g). Horizontal: in-register except j%4 in {0,3}
//  (1-float shuffle). One-sided boundary formulas at t==0 (g==0) / t==15 (g==3)
//  via extra uniform-branch shuffles. All shuffles executed by all lanes
//  (selects after, never inside divergent control flow).
// No LDS reuse, no barriers, no atomics -> deterministic.

#define NB 4096
#define HW 4096          // 64*64
#define CHW 8192         // 2*64*64

typedef float vf4 __attribute__((ext_vector_type(4)));

__device__ __forceinline__ vf4 shfl4(vf4 v, int src) {
    vf4 r;
    r.x = __shfl(v.x, src); r.y = __shfl(v.y, src);
    r.z = __shfl(v.z, src); r.w = __shfl(v.w, src);
    return r;
}
__device__ __forceinline__ vf4 sel4(bool c, vf4 a, vf4 b) {
    vf4 r;
    r.x = c ? a.x : b.x; r.y = c ? a.y : b.y;
    r.z = c ? a.z : b.z; r.w = c ? a.w : b.w;
    return r;
}

__global__ __launch_bounds__(256, 4) void darcy_fused_kernel(
    const float* __restrict__ mo, const float* __restrict__ tg,
    const float* __restrict__ x0, const float* __restrict__ var,
    float* __restrict__ ws_res, float* __restrict__ ws_d)
{
    constexpr float INV2D = 31.5f;            // 1/(2D), D=1/63
    constexpr float INVD2 = 3969.0f;          // 1/D^2
    constexpr float CLAMP = 27.6310211159f;

    const int lane = threadIdx.x & 63;
    const int wv   = threadIdx.x >> 6;
    const int b    = blockIdx.x * 4 + wv;
    const int g    = lane >> 4;
    const bool g0  = (g == 0), g3 = (g == 3);
    const bool cL  = ((lane & 15) == 0);      // owns col 0 (j=0 boundary)
    const bool cR  = ((lane & 15) == 15);     // owns col 63

    const vf4* p4 = (const vf4*)(x0 + (size_t)b * CHW);   // 1024 f4: p plane
    const vf4* q4 = p4 + 1024;                            // perm plane
    const vf4* m4 = (const vf4*)(mo + (size_t)b * CHW);   // 2048 f4
    const vf4* g4 = (const vf4*)(tg + (size_t)b * CHW);

    const int iu = (lane + 16) & 63;   // row+1 source (cur or next)
    const int id = (lane + 48) & 63;   // row-1 source (cur or prev)
    const int ix = (lane + 32) & 63;   // row+-2 source (boundary only)
    const int il = (lane + 63) & 63;   // lane-1
    const int ir = (lane + 1) & 63;    // lane+1

    float rsum = 0.0f, dsum = 0.0f;

    vf4 pc = p4[lane], qc = q4[lane];  // t=0 block (rows 0..3)
    vf4 pv = pc, qv = qc;              // prev block (unused at t=0, masked)

    #pragma unroll 4
    for (int t = 0; t < 16; ++t) {
        // ---- prefetch next 4-row block ----
        vf4 pn_, qn_;
        if (t < 15) { pn_ = p4[(t + 1) * 64 + lane]; qn_ = q4[(t + 1) * 64 + lane]; }
        else        { pn_ = pc; qn_ = qc; }          // garbage, masked by g3 selects

        // ---- fused data-loss streaming (nontemporal: zero reuse) ----
        vf4 a0 = __builtin_nontemporal_load(m4 + t * 128 + lane);
        vf4 a1 = __builtin_nontemporal_load(m4 + t * 128 + 64 + lane);
        vf4 e0 = a0 - __builtin_nontemporal_load(g4 + t * 128 + lane);
        vf4 e1 = a1 - __builtin_nontemporal_load(g4 + t * 128 + 64 + lane);
        dsum += e0.x*e0.x + e0.y*e0.y + e0.z*e0.z + e0.w*e0.w
              + e1.x*e1.x + e1.y*e1.y + e1.z*e1.z + e1.w*e1.w;

        // ---- vertical neighbors via lane+-16 (all shuffles unconditional) ----
        vf4 upc = shfl4(pc, iu), dnc = shfl4(pc, id);
        vf4 upq = shfl4(qc, iu), dnq = shfl4(qc, id);
        vf4 upn = shfl4(pn_, iu), dnp = shfl4(pv, id);
        vf4 uqn = shfl4(qn_, iu), dqp = shfl4(qv, id);
        vf4 upP = sel4(g3, upn, upc);      // row r+1 of p
        vf4 dnP = sel4(g0, dnp, dnc);      // row r-1 of p
        vf4 upQ = sel4(g3, uqn, upq);
        vf4 dnQ = sel4(g0, dqp, dnq);

        vf4 pd0  = (upP - dnP) * INV2D;
        vf4 pd00 = (upP - 2.0f * pc + dnP) * INVD2;
        vf4 qd0  = (upQ - dnQ) * INV2D;

        if (t == 0) {       // row 0 one-sided (g==0): rows 1,2,3 = upc, shfl+32, dnc
            vf4 r2 = shfl4(pc, ix);
            vf4 s2 = shfl4(qc, ix);
            vf4 od0  = (-3.0f * pc + 4.0f * upc - r2) * INV2D;
            vf4 od00 = (2.0f * pc - 5.0f * upc + 4.0f * r2 - dnc) * INVD2;
            vf4 oq0  = (-3.0f * qc + 4.0f * upq - s2) * INV2D;
            pd0  = sel4(g0, od0, pd0);
            pd00 = sel4(g0, od00, pd00);
            qd0  = sel4(g0, oq0, qd0);
        }
        if (t == 15) {      // row 63 one-sided (g==3): rows 62,61,60 = dnc, shfl+32, upc
            vf4 m2 = shfl4(pc, ix);
            vf4 s2 = shfl4(qc, ix);
            vf4 od0  = (3.0f * pc - 4.0f * dnc + m2) * INV2D;
            vf4 od00 = (2.0f * pc - 5.0f * dnc + 4.0f * m2 - upc) * INVD2;
            vf4 oq0  = (3.0f * qc - 4.0f * dnq + s2) * INV2D;
            pd0  = sel4(g3, od0, pd0);
            pd00 = sel4(g3, od00, pd00);
            qd0  = sel4(g3, oq0, qd0);
        }

        // ---- horizontal: only the float4 edges need neighbors ----
        float pL = __shfl(pc.w, il), pR = __shfl(pc.x, ir);
        float qL = __shfl(qc.w, il), qR = __shfl(qc.x, ir);

        // cell 0 (col 4cg): interior uses pL; j=0 one-sided in-register
        float pd1_0  = cL ? (-3.f*pc.x + 4.f*pc.y - pc.z) * INV2D
                          : (pc.y - pL) * INV2D;
        float pd11_0 = cL ? (2.f*pc.x - 5.f*pc.y + 4.f*pc.z - pc.w) * INVD2
                          : (pc.y - 2.f*pc.x + pL) * INVD2;
        float qd1_0  = cL ? (-3.f*qc.x + 4.f*qc.y - qc.z) * INV2D
                          : (qc.y - qL) * INV2D;
        // cells 1,2: fully in-register
        float pd1_1  = (pc.z - pc.x) * INV2D;
        float pd11_1 = (pc.z - 2.f*pc.y + pc.x) * INVD2;
        float qd1_1  = (qc.z - qc.x) * INV2D;
        float pd1_2  = (pc.w - pc.y) * INV2D;
        float pd11_2 = (pc.w - 2.f*pc.z + pc.y) * INVD2;
        float qd1_2  = (qc.w - qc.y) * INV2D;
        // cell 3 (col 4cg+3): interior uses pR; j=63 one-sided in-register
        float pd1_3  = cR ? (3.f*pc.w - 4.f*pc.z + pc.y) * INV2D
                          : (pR - pc.z) * INV2D;
        float pd11_3 = cR ? (2.f*pc.w - 5.f*pc.z + 4.f*pc.y - pc.x) * INVD2
                          : (pR - 2.f*pc.w + pc.z) * INVD2;
        float qd1_3  = cR ? (3.f*qc.w - 4.f*qc.z + qc.y) * INV2D
                          : (qR - qc.z) * INV2D;

        // ---- eq0 = -(perm*(pd00+pd11) + qd0*pd0 + qd1*pd1) ----
        rsum -= qc.x * (pd00.x + pd11_0) + qd0.x * pd0.x + qd1_0 * pd1_0;
        rsum -= qc.y * (pd00.y + pd11_1) + qd0.y * pd0.y + qd1_1 * pd1_1;
        rsum -= qc.z * (pd00.z + pd11_2) + qd0.z * pd0.z + qd1_2 * pd1_2;
        rsum -= qc.w * (pd00.w + pd11_3) + qd0.w * pd0.w + qd1_3 * pd1_3;

        // ---- boundary-condition terms ----
        if (t == 0)  rsum -= g0 ? (pd0.x + pd0.y + pd0.z + pd0.w) : 0.0f;
        if (t == 15) rsum += g3 ? (pd0.x + pd0.y + pd0.z + pd0.w) : 0.0f;
        rsum += cL ? pd1_0 : 0.0f;
        rsum -= cR ? pd1_3 : 0.0f;

        // rotate window
        pv = pc; qv = qc; pc = pn_; qc = qn_;
    }

    // ---- per-wave reduction (wave == batch) ----
    #pragma unroll
    for (int off = 32; off > 0; off >>= 1) {
        rsum += __shfl_down(rsum, off);
        dsum += __shfl_down(dsum, off);
    }
    if (lane == 0) {
        const float r = rsum * (1.0f / (64.0f * 64.0f * 3.0f));
        float res = 0.5f * r * r / var[b];
        ws_res[b] = fminf(res, CLAMP);
        ws_d[b]   = dsum;
    }
}

__global__ __launch_bounds__(256) void darcy_final_kernel(
    const float* __restrict__ ws_res, const float* __restrict__ ws_d,
    float* __restrict__ out)
{
    const int t = threadIdx.x;
    double rs = 0.0, ds = 0.0;
    for (int i = t; i < NB; i += 256) {
        rs += (double)ws_res[i];
        ds += (double)ws_d[i];
    }
    #pragma unroll
    for (int off = 32; off > 0; off >>= 1) {
        rs += __shfl_down(rs, off);
        ds += __shfl_down(ds, off);
    }
    __shared__ double red[8];
    const int wid = t >> 6, lane = t & 63;
    if (lane == 0) { red[wid] = rs; red[4 + wid] = ds; }
    __syncthreads();
    if (t == 0) {
        const double R  = red[0] + red[1] + red[2] + red[3];
        const double Dd = red[4] + red[5] + red[6] + red[7];
        out[0] = (float)(Dd / ((double)NB * (double)CHW) + R / (double)NB);
    }
}

extern "C" void kernel_launch(void* const* d_in, const int* in_sizes, int n_in,
                              void* d_out, int out_size, void* d_ws, size_t ws_size,
                              hipStream_t stream) {
    const float* mo  = (const float*)d_in[0];
    const float* tg  = (const float*)d_in[1];
    const float* x0  = (const float*)d_in[2];
    const float* var = (const float*)d_in[3];
    float* out = (float*)d_out;

    float* ws_res = (float*)d_ws;           // NB floats (clamped residual term)
    float* ws_d   = ws_res + NB;            // NB floats (data-loss partials)

    darcy_fused_kernel<<<NB / 4, 256, 0, stream>>>(mo, tg, x0, var, ws_res, ws_d);
    darcy_final_kernel<<<1, 256, 0, stream>>>(ws_res, ws_d, out);
}

// Round 8
// 72.811 us; speedup vs baseline: 3.6313x; 3.6313x over previous
//
#include <hip/hip_runtime.h>

// DarcyLoss: B=4096, C=2, H=W=64. Inputs (f32): model_out, target, x0_hat [B,2,64,64], var [B].
// loss = mean((mo-tg)^2) + mean_b( min(0.5*r_b^2/var_b, 27.6310211159) )
// r_b = (sum(eq0)+sum(bc)) / (64*64*3);  source f_s sums to 0 -> omitted.
//
// R8: R2's proven scalar-lane stencil (wave = batch, lane j = column j,
// horizontal via __shfl) with a DEEP register row-pipeline: 8-slot rolling
// window, prefetch distance 6 (row i+6 issued at iter i, consumed at i+5)
// -> ~6 p-loads + 6 q-loads (3 KB/wave) outstanding at all times.
// 16 waves/CU x 3 KB ~= 48 KB/CU in flight (Little's law target for >6 TB/s).
// Fully unrolled i-loop -> all window indices static -> registers, no scratch.
// mo/tg streaming fused (nontemporal float4, iters 1..32). No LDS, no barriers.

#define NB 4096
#define HW 4096          // 64*64
#define CHW 8192         // 2*64*64

typedef float vf4 __attribute__((ext_vector_type(4)));

__device__ __forceinline__ void hderiv2(float v, int j, float& d1, float& d11) {
    constexpr float INV2D = 31.5f, INVD2 = 3969.0f;
    float vm = __shfl(v, (j + 63) & 63);
    float vp = __shfl(v, (j + 1) & 63);
    float v2 = __shfl(v, (j == 0) ? 2 : 61);
    float v3 = __shfl(v, (j == 0) ? 3 : 60);
    d1  = (vp - vm) * INV2D;
    d11 = (vp - 2.0f * v + vm) * INVD2;
    if (j == 0)  { d1 = (-3.0f * v + 4.0f * vp - v2) * INV2D;
                   d11 = (2.0f * v - 5.0f * vp + 4.0f * v2 - v3) * INVD2; }
    if (j == 63) { d1 = ( 3.0f * v - 4.0f * vm + v2) * INV2D;
                   d11 = (2.0f * v - 5.0f * vm + 4.0f * v2 - v3) * INVD2; }
}

__device__ __forceinline__ float hderiv1(float v, int j) {
    constexpr float INV2D = 31.5f;
    float vm = __shfl(v, (j + 63) & 63);
    float vp = __shfl(v, (j + 1) & 63);
    float v2 = __shfl(v, (j == 0) ? 2 : 61);
    float d = (vp - vm) * INV2D;
    if (j == 0)  d = (-3.0f * v + 4.0f * vp - v2) * INV2D;
    if (j == 63) d = ( 3.0f * v - 4.0f * vm + v2) * INV2D;
    return d;
}

__global__ __launch_bounds__(256, 4) void darcy_wave_kernel(
    const float* __restrict__ mo, const float* __restrict__ tg,
    const float* __restrict__ x0, const float* __restrict__ var,
    float* __restrict__ ws_res, float* __restrict__ ws_d)
{
    constexpr float INV2D = 31.5f;
    constexpr float INVD2 = 3969.0f;
    constexpr float CLAMP = 27.6310211159f;

    const int wv = threadIdx.x >> 6;
    const int j  = threadIdx.x & 63;
    const int b  = blockIdx.x * 4 + wv;

    const float* pb = x0 + (size_t)b * CHW;        // p    plane
    const float* qb = pb + HW;                     // perm plane
    const vf4*   m4 = (const vf4*)(mo + (size_t)b * CHW);   // 2048 f4
    const vf4*   g4 = (const vf4*)(tg + (size_t)b * CHW);

    float rsum = 0.0f, dsum = 0.0f;

    // ---- 8-slot register row pipeline; preload rows 0..6 ----
    float ps[8], qs[8];
    #pragma unroll
    for (int k = 0; k < 7; ++k) {
        ps[k] = pb[(k << 6) + j];
        qs[k] = qb[(k << 6) + j];
    }

    // ---- row i = 0 (one-sided vertical), uses rows 0..3 ----
    {
        float pd1, pd11;
        hderiv2(ps[0], j, pd1, pd11);
        float qd1 = hderiv1(qs[0], j);
        float pd0  = (-3.0f * ps[0] + 4.0f * ps[1] - ps[2]) * INV2D;
        float pd00 = (2.0f * ps[0] - 5.0f * ps[1] + 4.0f * ps[2] - ps[3]) * INVD2;
        float qd0  = (-3.0f * qs[0] + 4.0f * qs[1] - qs[2]) * INV2D;
        rsum += -qs[0] * (pd00 + pd11) - qd0 * pd0 - qd1 * pd1 - pd0;   // bc(i=0)
        rsum += (j == 0) ? pd1 : 0.0f;
        rsum -= (j == 63) ? pd1 : 0.0f;
    }

    // ---- rows 1..62, fully unrolled; prefetch row i+6 at iter i ----
    #pragma unroll
    for (int i = 1; i <= 62; ++i) {
        if (i + 6 <= 63) {
            ps[(i + 6) & 7] = pb[((i + 6) << 6) + j];
            qs[(i + 6) & 7] = qb[((i + 6) << 6) + j];
        }
        if (i <= 32) {   // fused data-loss chunk i-1 (nontemporal: zero reuse)
            vf4 a = __builtin_nontemporal_load(m4 + ((i - 1) << 6) + j);
            vf4 c = __builtin_nontemporal_load(g4 + ((i - 1) << 6) + j);
            vf4 e = a - c;
            dsum += e.x * e.x + e.y * e.y + e.z * e.z + e.w * e.w;
        }

        const float pm = ps[(i - 1) & 7], pc = ps[i & 7], pp = ps[(i + 1) & 7];
        const float qm = qs[(i - 1) & 7], qc = qs[i & 7], qp = qs[(i + 1) & 7];

        float pd1, pd11;
        hderiv2(pc, j, pd1, pd11);
        float qd1 = hderiv1(qc, j);
        float pd0  = (pp - pm) * INV2D;
        float pd00 = (pp - 2.0f * pc + pm) * INVD2;
        float qd0  = (qp - qm) * INV2D;
        rsum += -qc * (pd00 + pd11) - qd0 * pd0 - qd1 * pd1;
        rsum += (j == 0) ? pd1 : 0.0f;
        rsum -= (j == 63) ? pd1 : 0.0f;
    }

    // ---- row i = 63 (one-sided vertical); rows 60..63 = slots 4,5,6,7 ----
    {
        const float p63 = ps[7], p62 = ps[6], p61 = ps[5], p60 = ps[4];
        const float q63 = qs[7], q62 = qs[6], q61 = qs[5];
        float pd1, pd11;
        hderiv2(p63, j, pd1, pd11);
        float qd1 = hderiv1(q63, j);
        float pd0  = (3.0f * p63 - 4.0f * p62 + p61) * INV2D;
        float pd00 = (2.0f * p63 - 5.0f * p62 + 4.0f * p61 - p60) * INVD2;
        float qd0  = (3.0f * q63 - 4.0f * q62 + q61) * INV2D;
        rsum += -q63 * (pd00 + pd11) - qd0 * pd0 - qd1 * pd1 + pd0;   // bc(i=63)
        rsum += (j == 0) ? pd1 : 0.0f;
        rsum -= (j == 63) ? pd1 : 0.0f;
    }

    // ---- per-wave reduction (wave == batch) ----
    #pragma unroll
    for (int off = 32; off > 0; off >>= 1) {
        rsum += __shfl_down(rsum, off);
        dsum += __shfl_down(dsum, off);
    }
    if (j == 0) {
        const float r = rsum * (1.0f / (64.0f * 64.0f * 3.0f));
        float res = 0.5f * r * r / var[b];
        ws_res[b] = fminf(res, CLAMP);
        ws_d[b]   = dsum;
    }
}

__global__ __launch_bounds__(256) void darcy_final_kernel(
    const float* __restrict__ ws_res, const float* __restrict__ ws_d,
    float* __restrict__ out)
{
    const int t = threadIdx.x;
    double rs = 0.0, ds = 0.0;
    for (int i = t; i < NB; i += 256) {
        rs += (double)ws_res[i];
        ds += (double)ws_d[i];
    }
    #pragma unroll
    for (int off = 32; off > 0; off >>= 1) {
        rs += __shfl_down(rs, off);
        ds += __shfl_down(ds, off);
    }
    __shared__ double red[8];
    const int wid = t >> 6, lane = t & 63;
    if (lane == 0) { red[wid] = rs; red[4 + wid] = ds; }
    __syncthreads();
    if (t == 0) {
        const double R  = red[0] + red[1] + red[2] + red[3];
        const double Dd = red[4] + red[5] + red[6] + red[7];
        out[0] = (float)(Dd / ((double)NB * (double)CHW) + R / (double)NB);
    }
}

extern "C" void kernel_launch(void* const* d_in, const int* in_sizes, int n_in,
                              void* d_out, int out_size, void* d_ws, size_t ws_size,
                              hipStream_t stream) {
    const float* mo  = (const float*)d_in[0];
    const float* tg  = (const float*)d_in[1];
    const float* x0  = (const float*)d_in[2];
    const float* var = (const float*)d_in[3];
    float* out = (float*)d_out;

    float* ws_res = (float*)d_ws;           // NB floats (clamped residual term)
    float* ws_d   = ws_res + NB;            // NB floats (data-loss partials)

    darcy_wave_kernel<<<NB / 4, 256, 0, stream>>>(mo, tg, x0, var, ws_res, ws_d);
    darcy_final_kernel<<<1, 256, 0, stream>>>(ws_res, ws_d, out);
}